// Round 7
// baseline (277.577 us; speedup 1.0000x reference)
//
#include <hip/hip_runtime.h>
#include <math.h>

typedef __bf16 bf16;
typedef __attribute__((ext_vector_type(8))) __bf16 bf16x8;
typedef __attribute__((ext_vector_type(4))) float f32x4;

#define CDIV(a,b) (((a)+(b)-1)/(b))

// ---------------------------------------------------------------------------
// B=16, L=1024, U=512, H=2. M = 16384. fp32 I/O, bf16 internal.
// R7: transpose fused into highway-2 epilogue (LDS bounce, coalesced xT
// writes); wprep+init_conv+memset merged into one prep kernel. 6 dispatches.
// ---------------------------------------------------------------------------

__device__ __forceinline__ void load_lds16(const bf16* g, bf16* l) {
  __builtin_amdgcn_global_load_lds(
      (const __attribute__((address_space(1))) unsigned int*)(g),
      (__attribute__((address_space(3))) unsigned int*)(l), 16, 0, 0);
}

// ============================ plain NT GEMM ================================
struct GemmArgs {
  const bf16* A; const bf16* B; bf16* C;
  int K, lda, ldb, ldc;
  long long Ab, Bb, Cb;
  const float* s1; const float* s2; const float* abp; // EPI1; s1=lsum for EPI4
  float* lsum;                   // EPI 1: row sums of E
  int L;
  int gxsh, gysh;
};

// C[M,N] = A[M,K] @ Bt[N,K]^T. Tile 128x128, BK=64, 4 waves 2x2, 4x4 MFMA
// 16x16x32. global_load_lds w=16, XOR-swizzled granules (0 bank conflicts,
// R4-verified). XCD swizzle keeps per-XCD working set in L2 (R4-verified).
template<int EPI>   // 1 = scores->E + lsum atomics, 4 = PV * (1/l)
__global__ __launch_bounds__(256, 4)
void gemm_nt(GemmArgs g) {
  __shared__ bf16 As[128 * 64];
  __shared__ bf16 Bs[128 * 64];
  const int tid = threadIdx.x;
  const int bid = blockIdx.x;
  const int xcd = bid & 7;
  const int t = bid >> 3;
  const int bx = t & ((1 << g.gxsh) - 1);
  const int r  = t >> g.gxsh;
  const int Rx = gridDim.x >> (3 + g.gxsh);
  const int gr = xcd * Rx + r;
  const int by = gr & ((1 << g.gysh) - 1);
  const int bz = gr >> g.gysh;

  const bf16* Ag = g.A + (long long)bz * g.Ab + (long long)(by * 128) * g.lda;
  const bf16* Bg = g.B + (long long)bz * g.Bb + (long long)(bx * 128) * g.ldb;
  const int wid = tid >> 6, lane = tid & 63;
  const int wm = (wid >> 1) << 6;
  const int wn = (wid & 1) << 6;
  const int lr = lane & 15, lq = lane >> 4;

  f32x4 acc[4][4];
#pragma unroll
  for (int i = 0; i < 4; i++)
#pragma unroll
    for (int j = 0; j < 4; j++) acc[i][j] = f32x4{0.f, 0.f, 0.f, 0.f};

  const int srow8 = (tid >> 3) & 7;
  const int skc   = (tid & 7) ^ srow8;
  const int lswz  = (lr & 7);

  for (int k0 = 0; k0 < g.K; k0 += 64) {
    __syncthreads();
#pragma unroll
    for (int j = 0; j < 4; j++) {
      const int ci = (tid >> 6) * 4 + j;
      const int row = ci * 8 + srow8;
      load_lds16(Ag + (long long)row * g.lda + k0 + skc * 8, As + ci * 512);
      load_lds16(Bg + (long long)row * g.ldb + k0 + skc * 8, Bs + ci * 512);
    }
    __syncthreads();
#pragma unroll
    for (int ks = 0; ks < 2; ks++) {
      bf16x8 af[4], bfr[4];
      const int kx = (ks * 4 + lq) ^ lswz;
#pragma unroll
      for (int i = 0; i < 4; i++)
        af[i] = *(const bf16x8*)(&As[(wm + i * 16 + lr) * 64 + kx * 8]);
#pragma unroll
      for (int j = 0; j < 4; j++)
        bfr[j] = *(const bf16x8*)(&Bs[(wn + j * 16 + lr) * 64 + kx * 8]);
#pragma unroll
      for (int i = 0; i < 4; i++)
#pragma unroll
        for (int j = 0; j < 4; j++)
          acc[i][j] = __builtin_amdgcn_mfma_f32_16x16x32_bf16(af[i], bfr[j], acc[i][j], 0, 0, 0);
    }
  }

  bf16* Cg = g.C + (long long)bz * g.Cb;
#pragma unroll
  for (int i = 0; i < 4; i++) {
#pragma unroll
    for (int v = 0; v < 4; v++) {
      int row = by * 128 + wm + i * 16 + lq * 4 + v;
      float srow = 0.f;
      if (EPI == 1) srow = g.s1[bz * g.L + row] + g.abp[0];
      if (EPI == 4) srow = 1.f / g.s1[bz * g.L + row];   // reciprocal of lsum
      float psum = 0.f;
#pragma unroll
      for (int j = 0; j < 4; j++) {
        int col = bx * 128 + wn + j * 16 + lr;
        float val = acc[i][j][v];
        if (EPI == 1) {
          val += srow + g.s2[bz * g.L + col];
          val = fminf(fmaxf(val, 0.f), 60.f);
          val = __expf(val);
          bf16 eb = (bf16)val;
          psum += (float)eb;
          Cg[(long long)row * g.ldc + col] = eb;
        } else {
          val *= srow;
          Cg[(long long)row * g.ldc + col] = (bf16)val;
        }
      }
      if (EPI == 1) {
        psum += __shfl_xor(psum, 1, 64);
        psum += __shfl_xor(psum, 2, 64);
        psum += __shfl_xor(psum, 4, 64);
        psum += __shfl_xor(psum, 8, 64);
        if (lr == 0) atomicAdd(&g.lsum[bz * g.L + row], psum);
      }
    }
  }
}

// ===================== dual-column fused-gating GEMM =======================
// Output cols n in [0,512); weight rows n (t/z) and n+512 (c/r) interleaved in
// the B tile. acc[i][j] j<2 = t-half, j>=2 = c-half of the same cols.
struct DualArgs {
  const bf16* A; const bf16* A2;   // A2 = rows for k>=512 (final); else == A
  const bf16* Bt;
  void* C; const void* xres;
  const float* bias_t; const float* bias_c;
  int K, ldb;
  const float* aW;                 // EPI 2
  float* s1a; float* s2a;          // EPI 2: atomic partial dots
  bf16* q;                         // EPI 2: x * w3
  bf16* xT;                        // EPI 2: per-batch transpose of x2
};

template<int EPI>  // 0 = highway, 2 = highway + s1/s2/q/xT fusion, 1 = final
__global__ __launch_bounds__(256, 4)
void gemm_dual(DualArgs g) {
  __shared__ bf16 smem[2 * 128 * 64];      // As | Bs; reused as Ts in EPI 2
  bf16* As = smem;
  bf16* Bs = smem + 8192;
  const int tid = threadIdx.x;
  const int bid = blockIdx.x;
  const int xcd = bid & 7;
  const int t = bid >> 3;
  const int bx = t & 7;
  const int r  = t >> 3;
  const int Rx = gridDim.x >> 6;
  const int by = xcd * Rx + r;

  const int wid = tid >> 6, lane = tid & 63;
  const int wm = (wid >> 1) << 6;
  const int wn = (wid & 1) << 6;
  const int lr = lane & 15, lq = lane >> 4;

  f32x4 acc[4][4];
#pragma unroll
  for (int i = 0; i < 4; i++)
#pragma unroll
    for (int j = 0; j < 4; j++) acc[i][j] = f32x4{0.f, 0.f, 0.f, 0.f};

  const int srow8 = (tid >> 3) & 7;
  const int skc   = (tid & 7) ^ srow8;
  const int lswz  = (lr & 7);
  const long long abase = (long long)(by * 128) * 512;

  for (int k0 = 0; k0 < g.K; k0 += 64) {
    const bf16* Ak = (k0 < 512) ? g.A : g.A2;
    const int kk = k0 & 511;
    __syncthreads();
#pragma unroll
    for (int j = 0; j < 4; j++) {
      const int ci = (tid >> 6) * 4 + j;
      const int bn = ci * 8 + srow8;
      load_lds16(Ak + abase + (long long)bn * 512 + kk + skc * 8, As + ci * 512);
      const int grp = bn >> 5, r5 = bn & 31;
      const int grow = ((grp & 1) << 9) + bx * 64 + ((grp >> 1) << 5) + r5;
      load_lds16(g.Bt + (long long)grow * g.ldb + k0 + skc * 8, Bs + ci * 512);
    }
    __syncthreads();
#pragma unroll
    for (int ks = 0; ks < 2; ks++) {
      bf16x8 af[4], bfr[4];
      const int kx = (ks * 4 + lq) ^ lswz;
#pragma unroll
      for (int i = 0; i < 4; i++)
        af[i] = *(const bf16x8*)(&As[(wm + i * 16 + lr) * 64 + kx * 8]);
#pragma unroll
      for (int j = 0; j < 4; j++)
        bfr[j] = *(const bf16x8*)(&Bs[(wn + j * 16 + lr) * 64 + kx * 8]);
#pragma unroll
      for (int i = 0; i < 4; i++)
#pragma unroll
        for (int j = 0; j < 4; j++)
          acc[i][j] = __builtin_amdgcn_mfma_f32_16x16x32_bf16(af[i], bfr[j], acc[i][j], 0, 0, 0);
    }
  }

  const int colb = bx * 64 + (wn >> 1);
  bf16 xn_arr[4][4][2];
#pragma unroll
  for (int i = 0; i < 4; i++) {
#pragma unroll
    for (int v = 0; v < 4; v++) {
      int row = by * 128 + wm + i * 16 + lq * 4 + v;
      float p1s = 0.f, p2s = 0.f;
#pragma unroll
      for (int j = 0; j < 2; j++) {
        int col = colb + j * 16 + lr;
        long long idx = (long long)row * 512 + col;
        float p0 = acc[i][j][v] + g.bias_t[col];
        float p1 = acc[i][j + 2][v] + g.bias_c[col];
        if (EPI == 1) {
          float z = 1.f / (1.f + __expf(-p0));
          float rr = 1.f / (1.f + __expf(-p1));
          float x = ((const float*)g.xres)[idx];
          ((float*)g.C)[idx] = rr * x + z * z;
        } else {
          float tt = fmaxf(p0, 0.f);
          float c = 1.f / (1.f + __expf(-p1));
          float x = (float)((const bf16*)g.xres)[idx];
          bf16 xn = (bf16)(tt * c + x * (1.f - c));
          ((bf16*)g.C)[idx] = xn;
          if (EPI == 2) {
            xn_arr[i][v][j] = xn;
            float xf = (float)xn;
            p1s += xf * g.aW[col];
            p2s += xf * g.aW[512 + col];
            g.q[idx] = (bf16)(xf * g.aW[1024 + col]);
          }
        }
      }
      if (EPI == 2) {
        p1s += __shfl_xor(p1s, 1, 64);
        p1s += __shfl_xor(p1s, 2, 64);
        p1s += __shfl_xor(p1s, 4, 64);
        p1s += __shfl_xor(p1s, 8, 64);
        p2s += __shfl_xor(p2s, 1, 64);
        p2s += __shfl_xor(p2s, 2, 64);
        p2s += __shfl_xor(p2s, 4, 64);
        p2s += __shfl_xor(p2s, 8, 64);
        if (lr == 0) {
          atomicAdd(&g.s1a[row], p1s);
          atomicAdd(&g.s2a[row], p2s);
        }
      }
    }
  }

  if (EPI == 2) {
    // fused transpose: this block owns a 128x64 tile of x2 (rows by*128+,
    // cols bx*64+). Bounce through LDS (stride 136: rows 16B-aligned, ~2-way
    // banks), then coalesced write to xT[b][d][j].
    bf16* Ts = smem;                       // 64*136 bf16 = 17408 B, fits 32 KB
    __syncthreads();                       // all waves done with As/Bs
#pragma unroll
    for (int i = 0; i < 4; i++)
#pragma unroll
      for (int v = 0; v < 4; v++)
#pragma unroll
        for (int j = 0; j < 2; j++) {
          int rloc = wm + i * 16 + lq * 4 + v;
          int cloc = (wn >> 1) + j * 16 + lr;
          Ts[cloc * 136 + rloc] = xn_arr[i][v][j];
        }
    __syncthreads();
    const int b = by >> 3;
    bf16* dst = g.xT + (long long)b * 524288 + ((by & 7) * 128);
#pragma unroll
    for (int it = 0; it < 2; it++) {
      int d = (tid >> 3) + it * 32;
      int jb = (tid & 7) * 16;
      bf16x8 v0 = *(const bf16x8*)(&Ts[d * 136 + jb]);
      bf16x8 v1 = *(const bf16x8*)(&Ts[d * 136 + jb + 8]);
      long long o = (long long)(bx * 64 + d) * 1024 + jb;
      *(bf16x8*)(dst + o) = v0;
      *(bf16x8*)(dst + o + 8) = v1;
    }
  }
}

// ============================ prep kernel ==================================
// Segmented domain: [0,N1) w1T, [N1,N1+N2) w2T, then biases, then fp32->bf16
// input conversion, then zeroing the atomic-reduction buffer.
__global__ void prep(const float* tW, const float* tb, const float* cW, const float* cb,
                     const float* frW, const float* frb, const float* ffW, const float* ffb,
                     const float* inp, bf16* xb0,
                     bf16* w1T, bf16* w2T, float* bias1, float* bias2, float* sred) {
  const long long idx = (long long)blockIdx.x * 256 + threadIdx.x;
  const long long N1 = 1048576, N2 = 1048576;
  const long long T0 = N1 + N2 + 3072;        // weights + biases
  const long long T1 = T0 + 1048576;          // + input conversion (x8)
  const long long T2 = T1 + 12288;            // + sred zero (x4)
  if (idx < N1) {
    int l = (int)(idx >> 19);
    int rem = (int)(idx & 524287);
    int n = rem >> 9, k = rem & 511;
    float v = (n < 512) ? tW[l * 262144 + k * 512 + n]
                        : cW[l * 262144 + k * 512 + (n - 512)];
    w1T[idx] = (bf16)v;
  } else if (idx < N1 + N2) {
    int j = (int)(idx - N1);
    int n = j >> 10, k = j & 1023;
    float v = (n < 512) ? ffW[k * 512 + n] : frW[k * 512 + (n - 512)];
    w2T[j] = (bf16)v;
  } else if (idx < T0) {
    int j = (int)(idx - (N1 + N2));
    if (j < 2048) {
      int l = j >> 10, n = j & 1023;
      bias1[j] = (n < 512) ? tb[l * 512 + n] : cb[l * 512 + (n - 512)];
    } else {
      int n = j - 2048;
      bias2[n] = (n < 512) ? ffb[n] : frb[n - 512];
    }
  } else if (idx < T1) {
    long long i8 = (idx - T0) * 8;
    bf16x8 o;
#pragma unroll
    for (int k = 0; k < 8; k++) o[k] = (bf16)inp[i8 + k];
    *(bf16x8*)(xb0 + i8) = o;
  } else if (idx < T2) {
    long long z = (idx - T1) * 4;
    *(f32x4*)(sred + z) = f32x4{0.f, 0.f, 0.f, 0.f};
  }
}

extern "C" void kernel_launch(void* const* d_in, const int* in_sizes, int n_in,
                              void* d_out, int out_size, void* d_ws, size_t ws_size,
                              hipStream_t stream) {
  const float* inp = (const float*)d_in[0];
  const float* tW  = (const float*)d_in[1];
  const float* tb  = (const float*)d_in[2];
  const float* cW  = (const float*)d_in[3];
  const float* cb  = (const float*)d_in[4];
  const float* aW  = (const float*)d_in[5];
  const float* ab  = (const float*)d_in[6];
  const float* frW = (const float*)d_in[7];
  const float* frb = (const float*)d_in[8];
  const float* ffW = (const float*)d_in[9];
  const float* ffb = (const float*)d_in[10];
  float* out = (float*)d_out;

  char* p = (char*)d_ws;
  auto alloc = [&](size_t bytes) { char* r = p; p += (bytes + 255) & ~size_t(255); return r; };
  bf16* xb0   = (bf16*) alloc(16777216);
  bf16* x1    = (bf16*) alloc(16777216);
  bf16* x2    = (bf16*) alloc(16777216);
  bf16* q16   = (bf16*) alloc(16777216);
  bf16* xT16  = (bf16*) alloc(16777216);
  bf16* att16 = (bf16*) alloc(16777216);
  bf16* E16   = (bf16*) alloc(33554432);
  float* sred = (float*)alloc(196608);     // s1 | s2 | lsum
  bf16* w1T   = (bf16*) alloc(2097152);
  bf16* w2T   = (bf16*) alloc(2097152);
  float* bias1= (float*)alloc(8192);
  float* bias2= (float*)alloc(4096);
  float* s1 = sred, *s2 = sred + 16384, *lsum = sred + 32768;

  prep<<<CDIV(1048576 + 1048576 + 3072 + 1048576 + 12288, 256), 256, 0, stream>>>(
      tW, tb, cW, cb, frW, frb, ffW, ffb, inp, xb0, w1T, w2T, bias1, bias2, sred);

  {  // highway 1
    DualArgs g{};
    g.A = xb0; g.A2 = xb0; g.Bt = w1T;
    g.C = x1; g.xres = xb0;
    g.bias_t = bias1; g.bias_c = bias1 + 512;
    g.K = 512; g.ldb = 512;
    gemm_dual<0><<<1024, 256, 0, stream>>>(g);
  }
  {  // highway 2 + fused s1/s2/q + fused transpose
    DualArgs g{};
    g.A = x1; g.A2 = x1; g.Bt = w1T + 524288;
    g.C = x2; g.xres = x1;
    g.bias_t = bias1 + 1024; g.bias_c = bias1 + 1536;
    g.K = 512; g.ldb = 512;
    g.aW = aW; g.s1a = s1; g.s2a = s2; g.q = q16; g.xT = xT16;
    gemm_dual<2><<<1024, 256, 0, stream>>>(g);
  }
  {  // scores: E = exp(relu(Q K^T + s1 + s2 + ab)), row sums into lsum
    GemmArgs g{};
    g.A = q16; g.B = x2; g.C = E16;
    g.K = 512; g.lda = 512; g.ldb = 512; g.ldc = 1024;
    g.Ab = 524288; g.Bb = 524288; g.Cb = 1048576;
    g.s1 = s1; g.s2 = s2; g.abp = ab; g.lsum = lsum; g.L = 1024;
    g.gxsh = 3; g.gysh = 3;
    gemm_nt<1><<<1024, 256, 0, stream>>>(g);
  }
  {  // att = (E @ x) / l -> att16
    GemmArgs g{};
    g.A = E16; g.B = xT16; g.C = att16;
    g.K = 1024; g.lda = 1024; g.ldb = 1024; g.ldc = 512;
    g.Ab = 1048576; g.Bb = 524288; g.Cb = 524288;
    g.s1 = lsum; g.L = 1024;
    g.gxsh = 2; g.gysh = 3;
    gemm_nt<4><<<512, 256, 0, stream>>>(g);
  }
  {  // final: out = r*inp + z*z, z/r = sigmoid([xb0|att] @ [ffW|frW] + b)
    DualArgs g{};
    g.A = xb0; g.A2 = att16; g.Bt = w2T;
    g.C = out; g.xres = inp;
    g.bias_t = bias2; g.bias_c = bias2 + 512;
    g.K = 1024; g.ldb = 1024;
    gemm_dual<1><<<1024, 256, 0, stream>>>(g);
  }
}

// Round 9
// 265.431 us; speedup vs baseline: 1.0458x; 1.0458x over previous
//
#include <hip/hip_runtime.h>
#include <math.h>

typedef __bf16 bf16;
typedef __attribute__((ext_vector_type(8))) __bf16 bf16x8;
typedef __attribute__((ext_vector_type(4))) float f32x4;

#define CDIV(a,b) (((a)+(b)-1)/(b))

// ---------------------------------------------------------------------------
// B=16, L=1024, U=512, H=2. M = 16384. fp32 I/O, bf16 internal.
// R9 = R8 with the prep grid bug fixed: input-conversion segment needs 4096
// blocks (M*U/2048), R8 gave it 512 -> 7/8 of xb0 stayed poison.
// ---------------------------------------------------------------------------

__device__ __forceinline__ void load_lds16(const bf16* g, bf16* l) {
  __builtin_amdgcn_global_load_lds(
      (const __attribute__((address_space(1))) unsigned int*)(g),
      (__attribute__((address_space(3))) unsigned int*)(l), 16, 0, 0);
}

// ============================ plain NT GEMM ================================
struct GemmArgs {
  const bf16* A; const bf16* B; bf16* C;
  int K, lda, ldb, ldc;
  long long Ab, Bb, Cb;
  const float* s1; const float* s2; const float* abp; // EPI1; s1=lsum for EPI4
  float* lsum;                   // EPI 1: row sums of E
  int L;
  int gxsh, gysh;
};

// C[M,N] = A[M,K] @ Bt[N,K]^T. Tile 128x128, BK=64, 4 waves 2x2, 4x4 MFMA
// 16x16x32. global_load_lds w=16, XOR-swizzled granules (0 bank conflicts,
// R4-verified). XCD swizzle keeps per-XCD working set in L2 (R4-verified).
template<int EPI>   // 1 = scores->E + lsum atomics, 4 = PV * (1/l)
__global__ __launch_bounds__(256, 4)
void gemm_nt(GemmArgs g) {
  __shared__ bf16 As[128 * 64];
  __shared__ bf16 Bs[128 * 64];
  const int tid = threadIdx.x;
  const int bid = blockIdx.x;
  const int xcd = bid & 7;
  const int t = bid >> 3;
  const int bx = t & ((1 << g.gxsh) - 1);
  const int r  = t >> g.gxsh;
  const int Rx = gridDim.x >> (3 + g.gxsh);
  const int gr = xcd * Rx + r;
  const int by = gr & ((1 << g.gysh) - 1);
  const int bz = gr >> g.gysh;

  const bf16* Ag = g.A + (long long)bz * g.Ab + (long long)(by * 128) * g.lda;
  const bf16* Bg = g.B + (long long)bz * g.Bb + (long long)(bx * 128) * g.ldb;
  const int wid = tid >> 6, lane = tid & 63;
  const int wm = (wid >> 1) << 6;
  const int wn = (wid & 1) << 6;
  const int lr = lane & 15, lq = lane >> 4;

  f32x4 acc[4][4];
#pragma unroll
  for (int i = 0; i < 4; i++)
#pragma unroll
    for (int j = 0; j < 4; j++) acc[i][j] = f32x4{0.f, 0.f, 0.f, 0.f};

  const int srow8 = (tid >> 3) & 7;
  const int skc   = (tid & 7) ^ srow8;
  const int lswz  = (lr & 7);

  for (int k0 = 0; k0 < g.K; k0 += 64) {
    __syncthreads();
#pragma unroll
    for (int j = 0; j < 4; j++) {
      const int ci = (tid >> 6) * 4 + j;
      const int row = ci * 8 + srow8;
      load_lds16(Ag + (long long)row * g.lda + k0 + skc * 8, As + ci * 512);
      load_lds16(Bg + (long long)row * g.ldb + k0 + skc * 8, Bs + ci * 512);
    }
    __syncthreads();
#pragma unroll
    for (int ks = 0; ks < 2; ks++) {
      bf16x8 af[4], bfr[4];
      const int kx = (ks * 4 + lq) ^ lswz;
#pragma unroll
      for (int i = 0; i < 4; i++)
        af[i] = *(const bf16x8*)(&As[(wm + i * 16 + lr) * 64 + kx * 8]);
#pragma unroll
      for (int j = 0; j < 4; j++)
        bfr[j] = *(const bf16x8*)(&Bs[(wn + j * 16 + lr) * 64 + kx * 8]);
#pragma unroll
      for (int i = 0; i < 4; i++)
#pragma unroll
        for (int j = 0; j < 4; j++)
          acc[i][j] = __builtin_amdgcn_mfma_f32_16x16x32_bf16(af[i], bfr[j], acc[i][j], 0, 0, 0);
    }
  }

  bf16* Cg = g.C + (long long)bz * g.Cb;
#pragma unroll
  for (int i = 0; i < 4; i++) {
#pragma unroll
    for (int v = 0; v < 4; v++) {
      int row = by * 128 + wm + i * 16 + lq * 4 + v;
      float srow = 0.f;
      if (EPI == 1) srow = g.s1[bz * g.L + row] + g.abp[0];
      if (EPI == 4) srow = 1.f / g.s1[bz * g.L + row];   // reciprocal of lsum
      float psum = 0.f;
#pragma unroll
      for (int j = 0; j < 4; j++) {
        int col = bx * 128 + wn + j * 16 + lr;
        float val = acc[i][j][v];
        if (EPI == 1) {
          val += srow + g.s2[bz * g.L + col];
          val = fminf(fmaxf(val, 0.f), 60.f);
          val = __expf(val);
          bf16 eb = (bf16)val;
          psum += (float)eb;
          Cg[(long long)row * g.ldc + col] = eb;
        } else {
          val *= srow;
          Cg[(long long)row * g.ldc + col] = (bf16)val;
        }
      }
      if (EPI == 1) {
        psum += __shfl_xor(psum, 1, 64);
        psum += __shfl_xor(psum, 2, 64);
        psum += __shfl_xor(psum, 4, 64);
        psum += __shfl_xor(psum, 8, 64);
        if (lr == 0) atomicAdd(&g.lsum[bz * g.L + row], psum);
      }
    }
  }
}

// ===================== dual-column fused-gating GEMM =======================
// Output cols n in [0,512); weight rows n (t/z) and n+512 (c/r) interleaved in
// the B tile. acc[i][j] j<2 = t-half, j>=2 = c-half of the same cols.
struct DualArgs {
  const bf16* A; const bf16* A2;   // A2 = rows for k>=512 (final); else == A
  const bf16* Bt;
  void* C; const void* xres;
  const float* bias_t; const float* bias_c;
  int K, ldb;
  const float* aW;                 // EPI 2
  float* s1a; float* s2a;          // EPI 2: atomic partial dots
  bf16* q;                         // EPI 2: x * w3
  bf16* xT;                        // EPI 2: per-batch transpose of x2
};

template<int EPI>  // 0 = highway, 2 = highway + s1/s2/q/xT fusion, 1 = final
__global__ __launch_bounds__(256, 4)
void gemm_dual(DualArgs g) {
  __shared__ bf16 smem[2 * 128 * 64];      // As | Bs; reused as Ts in EPI 2
  bf16* As = smem;
  bf16* Bs = smem + 8192;
  const int tid = threadIdx.x;
  const int bid = blockIdx.x;
  const int xcd = bid & 7;
  const int t = bid >> 3;
  const int bx = t & 7;
  const int r  = t >> 3;
  const int Rx = gridDim.x >> 6;
  const int by = xcd * Rx + r;

  const int wid = tid >> 6, lane = tid & 63;
  const int wm = (wid >> 1) << 6;
  const int wn = (wid & 1) << 6;
  const int lr = lane & 15, lq = lane >> 4;

  f32x4 acc[4][4];
#pragma unroll
  for (int i = 0; i < 4; i++)
#pragma unroll
    for (int j = 0; j < 4; j++) acc[i][j] = f32x4{0.f, 0.f, 0.f, 0.f};

  const int srow8 = (tid >> 3) & 7;
  const int skc   = (tid & 7) ^ srow8;
  const int lswz  = (lr & 7);
  const long long abase = (long long)(by * 128) * 512;

  for (int k0 = 0; k0 < g.K; k0 += 64) {
    const bf16* Ak = (k0 < 512) ? g.A : g.A2;
    const int kk = k0 & 511;
    __syncthreads();
#pragma unroll
    for (int j = 0; j < 4; j++) {
      const int ci = (tid >> 6) * 4 + j;
      const int bn = ci * 8 + srow8;
      load_lds16(Ak + abase + (long long)bn * 512 + kk + skc * 8, As + ci * 512);
      const int grp = bn >> 5, r5 = bn & 31;
      const int grow = ((grp & 1) << 9) + bx * 64 + ((grp >> 1) << 5) + r5;
      load_lds16(g.Bt + (long long)grow * g.ldb + k0 + skc * 8, Bs + ci * 512);
    }
    __syncthreads();
#pragma unroll
    for (int ks = 0; ks < 2; ks++) {
      bf16x8 af[4], bfr[4];
      const int kx = (ks * 4 + lq) ^ lswz;
#pragma unroll
      for (int i = 0; i < 4; i++)
        af[i] = *(const bf16x8*)(&As[(wm + i * 16 + lr) * 64 + kx * 8]);
#pragma unroll
      for (int j = 0; j < 4; j++)
        bfr[j] = *(const bf16x8*)(&Bs[(wn + j * 16 + lr) * 64 + kx * 8]);
#pragma unroll
      for (int i = 0; i < 4; i++)
#pragma unroll
        for (int j = 0; j < 4; j++)
          acc[i][j] = __builtin_amdgcn_mfma_f32_16x16x32_bf16(af[i], bfr[j], acc[i][j], 0, 0, 0);
    }
  }

  const int colb = bx * 64 + (wn >> 1);
  bf16 xn_arr[4][4][2];
#pragma unroll
  for (int i = 0; i < 4; i++) {
#pragma unroll
    for (int v = 0; v < 4; v++) {
      int row = by * 128 + wm + i * 16 + lq * 4 + v;
      float p1s = 0.f, p2s = 0.f;
#pragma unroll
      for (int j = 0; j < 2; j++) {
        int col = colb + j * 16 + lr;
        long long idx = (long long)row * 512 + col;
        float p0 = acc[i][j][v] + g.bias_t[col];
        float p1 = acc[i][j + 2][v] + g.bias_c[col];
        if (EPI == 1) {
          float z = 1.f / (1.f + __expf(-p0));
          float rr = 1.f / (1.f + __expf(-p1));
          float x = (float)((const bf16*)g.xres)[idx];   // bf16 residual
          ((float*)g.C)[idx] = rr * x + z * z;
        } else {
          float tt = fmaxf(p0, 0.f);
          float c = 1.f / (1.f + __expf(-p1));
          float x = (float)((const bf16*)g.xres)[idx];
          bf16 xn = (bf16)(tt * c + x * (1.f - c));
          ((bf16*)g.C)[idx] = xn;
          if (EPI == 2) {
            xn_arr[i][v][j] = xn;
            float xf = (float)xn;
            p1s += xf * g.aW[col];
            p2s += xf * g.aW[512 + col];
            g.q[idx] = (bf16)(xf * g.aW[1024 + col]);
          }
        }
      }
      if (EPI == 2) {
        p1s += __shfl_xor(p1s, 1, 64);
        p1s += __shfl_xor(p1s, 2, 64);
        p1s += __shfl_xor(p1s, 4, 64);
        p1s += __shfl_xor(p1s, 8, 64);
        p2s += __shfl_xor(p2s, 1, 64);
        p2s += __shfl_xor(p2s, 2, 64);
        p2s += __shfl_xor(p2s, 4, 64);
        p2s += __shfl_xor(p2s, 8, 64);
        if (lr == 0) {
          atomicAdd(&g.s1a[row], p1s);
          atomicAdd(&g.s2a[row], p2s);
        }
      }
    }
  }

  if (EPI == 2) {
    // fused transpose: 128x64 tile of x2 -> LDS (stride 136) -> coalesced xT
    bf16* Ts = smem;
    __syncthreads();
#pragma unroll
    for (int i = 0; i < 4; i++)
#pragma unroll
      for (int v = 0; v < 4; v++)
#pragma unroll
        for (int j = 0; j < 2; j++) {
          int rloc = wm + i * 16 + lq * 4 + v;
          int cloc = (wn >> 1) + j * 16 + lr;
          Ts[cloc * 136 + rloc] = xn_arr[i][v][j];
        }
    __syncthreads();
    const int b = by >> 3;
    bf16* dst = g.xT + (long long)b * 524288 + ((by & 7) * 128);
#pragma unroll
    for (int it = 0; it < 2; it++) {
      int d = (tid >> 3) + it * 32;
      int jb = (tid & 7) * 16;
      bf16x8 v0 = *(const bf16x8*)(&Ts[d * 136 + jb]);
      bf16x8 v1 = *(const bf16x8*)(&Ts[d * 136 + jb + 8]);
      long long o = (long long)(bx * 64 + d) * 1024 + jb;
      *(bf16x8*)(dst + o) = v0;
      *(bf16x8*)(dst + o + 8) = v1;
    }
  }
}

// ============================ prep kernel ==================================
// Block-segmented:
//   [0,256)      : w1T = [tW|cW]^T via 64x64 LDS-tiled transpose (coalesced)
//   [256,512)    : w2T = [ffW|frW]^T likewise
//   [512,4608)   : fp32 inputs -> bf16 xb0 (coalesced; 4096 blocks = M*U/2048)
//   [4608]       : biases + sred zeroing
__device__ __forceinline__ void tile_transpose(const float* src, int sld,
                                               bf16* dst, int dld,
                                               int k0, int n0, int tid) {
  __shared__ float tile[64][65];
  const int rr = tid >> 4, c4 = (tid & 15) * 4;
#pragma unroll
  for (int it = 0; it < 4; it++) {
    int r = rr + it * 16;
    f32x4 v = *(const f32x4*)(src + (long long)(k0 + r) * sld + n0 + c4);
    tile[r][c4] = v[0]; tile[r][c4 + 1] = v[1];
    tile[r][c4 + 2] = v[2]; tile[r][c4 + 3] = v[3];
  }
  __syncthreads();
  const int nl = tid >> 2, kb = (tid & 3) * 16;
  bf16x8 o0, o1;
#pragma unroll
  for (int kk = 0; kk < 8; kk++) o0[kk] = (bf16)tile[kb + kk][nl];
#pragma unroll
  for (int kk = 0; kk < 8; kk++) o1[kk] = (bf16)tile[kb + 8 + kk][nl];
  bf16* d = dst + (long long)(n0 + nl) * dld + k0 + kb;
  *(bf16x8*)d = o0;
  *(bf16x8*)(d + 8) = o1;
}

__global__ void prep(const float* tW, const float* tb, const float* cW, const float* cb,
                     const float* frW, const float* frb, const float* ffW, const float* ffb,
                     const float* inp, bf16* xb0,
                     bf16* w1T, bf16* w2T, float* bias1, float* bias2, float* sred) {
  const int bid = blockIdx.x, tid = threadIdx.x;
  if (bid < 256) {
    // w1T: four 512x512 transposes (l, half), 64 tiles each
    const int quad = bid >> 6, tile = bid & 63;
    const int l = quad >> 1, half = quad & 1;
    const float* src = (half ? cW : tW) + l * 262144;
    bf16* dst = w1T + l * 524288 + half * 262144;
    tile_transpose(src, 512, dst, 512, (tile >> 3) * 64, (tile & 7) * 64, tid);
  } else if (bid < 512) {
    // w2T: two 1024x512 transposes (half), 128 tiles each
    const int j = bid - 256;
    const int half = j >> 7, tile = j & 127;
    const float* src = half ? frW : ffW;
    bf16* dst = w2T + half * 524288;
    tile_transpose(src, 512, dst, 1024, (tile >> 3) * 64, (tile & 7) * 64, tid);
  } else if (bid < 4608) {
    long long i8 = (((long long)(bid - 512)) * 256 + tid) * 8;
    bf16x8 o;
#pragma unroll
    for (int k = 0; k < 8; k++) o[k] = (bf16)inp[i8 + k];
    *(bf16x8*)(xb0 + i8) = o;
  } else {
    for (int j = tid; j < 3072; j += 256) {
      if (j < 2048) {
        int l = j >> 10, n = j & 1023;
        bias1[j] = (n < 512) ? tb[l * 512 + n] : cb[l * 512 + (n - 512)];
      } else {
        int n = j - 2048;
        bias2[n] = (n < 512) ? ffb[n] : frb[n - 512];
      }
    }
    for (int j = tid; j < 12288; j += 256)
      *(f32x4*)(sred + j * 4) = f32x4{0.f, 0.f, 0.f, 0.f};
  }
}

extern "C" void kernel_launch(void* const* d_in, const int* in_sizes, int n_in,
                              void* d_out, int out_size, void* d_ws, size_t ws_size,
                              hipStream_t stream) {
  const float* inp = (const float*)d_in[0];
  const float* tW  = (const float*)d_in[1];
  const float* tb  = (const float*)d_in[2];
  const float* cW  = (const float*)d_in[3];
  const float* cb  = (const float*)d_in[4];
  const float* aW  = (const float*)d_in[5];
  const float* ab  = (const float*)d_in[6];
  const float* frW = (const float*)d_in[7];
  const float* frb = (const float*)d_in[8];
  const float* ffW = (const float*)d_in[9];
  const float* ffb = (const float*)d_in[10];
  float* out = (float*)d_out;

  char* p = (char*)d_ws;
  auto alloc = [&](size_t bytes) { char* r = p; p += (bytes + 255) & ~size_t(255); return r; };
  bf16* xb0   = (bf16*) alloc(16777216);
  bf16* x1    = (bf16*) alloc(16777216);
  bf16* x2    = (bf16*) alloc(16777216);
  bf16* q16   = (bf16*) alloc(16777216);
  bf16* xT16  = (bf16*) alloc(16777216);
  bf16* att16 = (bf16*) alloc(16777216);
  bf16* E16   = (bf16*) alloc(33554432);
  float* sred = (float*)alloc(196608);     // s1 | s2 | lsum
  bf16* w1T   = (bf16*) alloc(2097152);
  bf16* w2T   = (bf16*) alloc(2097152);
  float* bias1= (float*)alloc(8192);
  float* bias2= (float*)alloc(4096);
  float* s1 = sred, *s2 = sred + 16384, *lsum = sred + 32768;

  prep<<<4609, 256, 0, stream>>>(
      tW, tb, cW, cb, frW, frb, ffW, ffb, inp, xb0, w1T, w2T, bias1, bias2, sred);

  {  // highway 1
    DualArgs g{};
    g.A = xb0; g.A2 = xb0; g.Bt = w1T;
    g.C = x1; g.xres = xb0;
    g.bias_t = bias1; g.bias_c = bias1 + 512;
    g.K = 512; g.ldb = 512;
    gemm_dual<0><<<1024, 256, 0, stream>>>(g);
  }
  {  // highway 2 + fused s1/s2/q + fused transpose
    DualArgs g{};
    g.A = x1; g.A2 = x1; g.Bt = w1T + 524288;
    g.C = x2; g.xres = x1;
    g.bias_t = bias1 + 1024; g.bias_c = bias1 + 1536;
    g.K = 512; g.ldb = 512;
    g.aW = aW; g.s1a = s1; g.s2a = s2; g.q = q16; g.xT = xT16;
    gemm_dual<2><<<1024, 256, 0, stream>>>(g);
  }
  {  // scores: E = exp(relu(Q K^T + s1 + s2 + ab)), row sums into lsum
    GemmArgs g{};
    g.A = q16; g.B = x2; g.C = E16;
    g.K = 512; g.lda = 512; g.ldb = 512; g.ldc = 1024;
    g.Ab = 524288; g.Bb = 524288; g.Cb = 1048576;
    g.s1 = s1; g.s2 = s2; g.abp = ab; g.lsum = lsum; g.L = 1024;
    g.gxsh = 3; g.gysh = 3;
    gemm_nt<1><<<1024, 256, 0, stream>>>(g);
  }
  {  // att = (E @ x) / l -> att16
    GemmArgs g{};
    g.A = E16; g.B = xT16; g.C = att16;
    g.K = 1024; g.lda = 1024; g.ldb = 1024; g.ldc = 512;
    g.Ab = 1048576; g.Bb = 524288; g.Cb = 524288;
    g.s1 = lsum; g.L = 1024;
    g.gxsh = 2; g.gysh = 3;
    gemm_nt<4><<<512, 256, 0, stream>>>(g);
  }
  {  // final: out = r*x + z*z, z/r = sigmoid([xb0|att] @ [ffW|frW] + b)
    DualArgs g{};
    g.A = xb0; g.A2 = att16; g.Bt = w2T;
    g.C = out; g.xres = xb0;               // bf16 residual
    g.bias_t = bias2; g.bias_c = bias2 + 512;
    g.K = 1024; g.ldb = 1024;
    gemm_dual<1><<<1024, 256, 0, stream>>>(g);
  }
}

// Round 10
// 260.583 us; speedup vs baseline: 1.0652x; 1.0186x over previous
//
#include <hip/hip_runtime.h>
#include <math.h>

typedef __bf16 bf16;
typedef __attribute__((ext_vector_type(8))) __bf16 bf16x8;
typedef __attribute__((ext_vector_type(4))) float f32x4;

#define CDIV(a,b) (((a)+(b)-1)/(b))

// ---------------------------------------------------------------------------
// B=16, L=1024, U=512, H=2. M = 16384. fp32 I/O, bf16 internal.
// R10: PV GEMM retiled 128x64 -> 1024 blocks (was 512 = 2/CU, the only
// under-occupied GEMM). gemm_nt templated on N-tile width.
// ---------------------------------------------------------------------------

__device__ __forceinline__ void load_lds16(const bf16* g, bf16* l) {
  __builtin_amdgcn_global_load_lds(
      (const __attribute__((address_space(1))) unsigned int*)(g),
      (__attribute__((address_space(3))) unsigned int*)(l), 16, 0, 0);
}

// ============================ plain NT GEMM ================================
struct GemmArgs {
  const bf16* A; const bf16* B; bf16* C;
  int K, lda, ldb, ldc;
  long long Ab, Bb, Cb;
  const float* s1; const float* s2; const float* abp; // EPI1; s1=lsum for EPI4
  float* lsum;                   // EPI 1: row sums of E
  int L;
  int gxsh, gysh;
};

// C[M,N] = A[M,K] @ Bt[N,K]^T. Tile 128xTN, BK=64, 4 waves 2x2 (wave tile
// 64 x TN/2), MFMA 16x16x32. global_load_lds w=16, XOR-swizzled granules
// (0 bank conflicts, R4-verified). XCD swizzle for L2 locality (R4-verified).
template<int EPI, int TN>   // EPI: 1 = scores->E + lsum atomics, 4 = PV*(1/l)
__global__ __launch_bounds__(256, 4)
void gemm_nt(GemmArgs g) {
  constexpr int JN = TN / 32;            // B j-frags per wave; B chunks/quarter
  __shared__ bf16 As[128 * 64];
  __shared__ bf16 Bs[TN * 64];
  const int tid = threadIdx.x;
  const int bid = blockIdx.x;
  const int xcd = bid & 7;
  const int t = bid >> 3;
  const int bx = t & ((1 << g.gxsh) - 1);
  const int r  = t >> g.gxsh;
  const int Rx = gridDim.x >> (3 + g.gxsh);
  const int gr = xcd * Rx + r;
  const int by = gr & ((1 << g.gysh) - 1);
  const int bz = gr >> g.gysh;

  const bf16* Ag = g.A + (long long)bz * g.Ab + (long long)(by * 128) * g.lda;
  const bf16* Bg = g.B + (long long)bz * g.Bb + (long long)(bx * TN) * g.ldb;
  const int wid = tid >> 6, lane = tid & 63;
  const int wm = (wid >> 1) << 6;
  const int wn = (wid & 1) * (TN / 2);
  const int lr = lane & 15, lq = lane >> 4;

  f32x4 acc[4][JN];
#pragma unroll
  for (int i = 0; i < 4; i++)
#pragma unroll
    for (int j = 0; j < JN; j++) acc[i][j] = f32x4{0.f, 0.f, 0.f, 0.f};

  const int srow8 = (tid >> 3) & 7;
  const int skc   = (tid & 7) ^ srow8;
  const int lswz  = (lr & 7);

  for (int k0 = 0; k0 < g.K; k0 += 64) {
    __syncthreads();
#pragma unroll
    for (int j = 0; j < 4; j++) {
      const int ci = (tid >> 6) * 4 + j;
      const int row = ci * 8 + srow8;
      load_lds16(Ag + (long long)row * g.lda + k0 + skc * 8, As + ci * 512);
    }
#pragma unroll
    for (int j = 0; j < JN; j++) {
      const int ci = (tid >> 6) * JN + j;
      const int row = ci * 8 + srow8;
      load_lds16(Bg + (long long)row * g.ldb + k0 + skc * 8, Bs + ci * 512);
    }
    __syncthreads();
#pragma unroll
    for (int ks = 0; ks < 2; ks++) {
      bf16x8 af[4], bfr[JN];
      const int kx = (ks * 4 + lq) ^ lswz;
#pragma unroll
      for (int i = 0; i < 4; i++)
        af[i] = *(const bf16x8*)(&As[(wm + i * 16 + lr) * 64 + kx * 8]);
#pragma unroll
      for (int j = 0; j < JN; j++)
        bfr[j] = *(const bf16x8*)(&Bs[(wn + j * 16 + lr) * 64 + kx * 8]);
#pragma unroll
      for (int i = 0; i < 4; i++)
#pragma unroll
        for (int j = 0; j < JN; j++)
          acc[i][j] = __builtin_amdgcn_mfma_f32_16x16x32_bf16(af[i], bfr[j], acc[i][j], 0, 0, 0);
    }
  }

  bf16* Cg = g.C + (long long)bz * g.Cb;
#pragma unroll
  for (int i = 0; i < 4; i++) {
#pragma unroll
    for (int v = 0; v < 4; v++) {
      int row = by * 128 + wm + i * 16 + lq * 4 + v;
      float srow = 0.f;
      if (EPI == 1) srow = g.s1[bz * g.L + row] + g.abp[0];
      if (EPI == 4) srow = 1.f / g.s1[bz * g.L + row];   // reciprocal of lsum
      float psum = 0.f;
#pragma unroll
      for (int j = 0; j < JN; j++) {
        int col = bx * TN + wn + j * 16 + lr;
        float val = acc[i][j][v];
        if (EPI == 1) {
          val += srow + g.s2[bz * g.L + col];
          val = fminf(fmaxf(val, 0.f), 60.f);
          val = __expf(val);
          bf16 eb = (bf16)val;
          psum += (float)eb;
          Cg[(long long)row * g.ldc + col] = eb;
        } else {
          val *= srow;
          Cg[(long long)row * g.ldc + col] = (bf16)val;
        }
      }
      if (EPI == 1) {
        psum += __shfl_xor(psum, 1, 64);
        psum += __shfl_xor(psum, 2, 64);
        psum += __shfl_xor(psum, 4, 64);
        psum += __shfl_xor(psum, 8, 64);
        if (lr == 0) atomicAdd(&g.lsum[bz * g.L + row], psum);
      }
    }
  }
}

// ===================== dual-column fused-gating GEMM =======================
// Output cols n in [0,512); weight rows n (t/z) and n+512 (c/r) interleaved in
// the B tile. acc[i][j] j<2 = t-half, j>=2 = c-half of the same cols.
struct DualArgs {
  const bf16* A; const bf16* A2;   // A2 = rows for k>=512 (final); else == A
  const bf16* Bt;
  void* C; const void* xres;
  const float* bias_t; const float* bias_c;
  int K, ldb;
  const float* aW;                 // EPI 2
  float* s1a; float* s2a;          // EPI 2: atomic partial dots
  bf16* q;                         // EPI 2: x * w3
  bf16* xT;                        // EPI 2: per-batch transpose of x2
};

template<int EPI>  // 0 = highway, 2 = highway + s1/s2/q/xT fusion, 1 = final
__global__ __launch_bounds__(256, 4)
void gemm_dual(DualArgs g) {
  __shared__ bf16 smem[2 * 128 * 64];      // As | Bs; reused as Ts in EPI 2
  bf16* As = smem;
  bf16* Bs = smem + 8192;
  const int tid = threadIdx.x;
  const int bid = blockIdx.x;
  const int xcd = bid & 7;
  const int t = bid >> 3;
  const int bx = t & 7;
  const int r  = t >> 3;
  const int Rx = gridDim.x >> 6;
  const int by = xcd * Rx + r;

  const int wid = tid >> 6, lane = tid & 63;
  const int wm = (wid >> 1) << 6;
  const int wn = (wid & 1) << 6;
  const int lr = lane & 15, lq = lane >> 4;

  f32x4 acc[4][4];
#pragma unroll
  for (int i = 0; i < 4; i++)
#pragma unroll
    for (int j = 0; j < 4; j++) acc[i][j] = f32x4{0.f, 0.f, 0.f, 0.f};

  const int srow8 = (tid >> 3) & 7;
  const int skc   = (tid & 7) ^ srow8;
  const int lswz  = (lr & 7);
  const long long abase = (long long)(by * 128) * 512;

  for (int k0 = 0; k0 < g.K; k0 += 64) {
    const bf16* Ak = (k0 < 512) ? g.A : g.A2;
    const int kk = k0 & 511;
    __syncthreads();
#pragma unroll
    for (int j = 0; j < 4; j++) {
      const int ci = (tid >> 6) * 4 + j;
      const int bn = ci * 8 + srow8;
      load_lds16(Ak + abase + (long long)bn * 512 + kk + skc * 8, As + ci * 512);
      const int grp = bn >> 5, r5 = bn & 31;
      const int grow = ((grp & 1) << 9) + bx * 64 + ((grp >> 1) << 5) + r5;
      load_lds16(g.Bt + (long long)grow * g.ldb + k0 + skc * 8, Bs + ci * 512);
    }
    __syncthreads();
#pragma unroll
    for (int ks = 0; ks < 2; ks++) {
      bf16x8 af[4], bfr[4];
      const int kx = (ks * 4 + lq) ^ lswz;
#pragma unroll
      for (int i = 0; i < 4; i++)
        af[i] = *(const bf16x8*)(&As[(wm + i * 16 + lr) * 64 + kx * 8]);
#pragma unroll
      for (int j = 0; j < 4; j++)
        bfr[j] = *(const bf16x8*)(&Bs[(wn + j * 16 + lr) * 64 + kx * 8]);
#pragma unroll
      for (int i = 0; i < 4; i++)
#pragma unroll
        for (int j = 0; j < 4; j++)
          acc[i][j] = __builtin_amdgcn_mfma_f32_16x16x32_bf16(af[i], bfr[j], acc[i][j], 0, 0, 0);
    }
  }

  const int colb = bx * 64 + (wn >> 1);
  bf16 xn_arr[4][4][2];
#pragma unroll
  for (int i = 0; i < 4; i++) {
#pragma unroll
    for (int v = 0; v < 4; v++) {
      int row = by * 128 + wm + i * 16 + lq * 4 + v;
      float p1s = 0.f, p2s = 0.f;
#pragma unroll
      for (int j = 0; j < 2; j++) {
        int col = colb + j * 16 + lr;
        long long idx = (long long)row * 512 + col;
        float p0 = acc[i][j][v] + g.bias_t[col];
        float p1 = acc[i][j + 2][v] + g.bias_c[col];
        if (EPI == 1) {
          float z = 1.f / (1.f + __expf(-p0));
          float rr = 1.f / (1.f + __expf(-p1));
          float x = (float)((const bf16*)g.xres)[idx];   // bf16 residual
          ((float*)g.C)[idx] = rr * x + z * z;
        } else {
          float tt = fmaxf(p0, 0.f);
          float c = 1.f / (1.f + __expf(-p1));
          float x = (float)((const bf16*)g.xres)[idx];
          bf16 xn = (bf16)(tt * c + x * (1.f - c));
          ((bf16*)g.C)[idx] = xn;
          if (EPI == 2) {
            xn_arr[i][v][j] = xn;
            float xf = (float)xn;
            p1s += xf * g.aW[col];
            p2s += xf * g.aW[512 + col];
            g.q[idx] = (bf16)(xf * g.aW[1024 + col]);
          }
        }
      }
      if (EPI == 2) {
        p1s += __shfl_xor(p1s, 1, 64);
        p1s += __shfl_xor(p1s, 2, 64);
        p1s += __shfl_xor(p1s, 4, 64);
        p1s += __shfl_xor(p1s, 8, 64);
        p2s += __shfl_xor(p2s, 1, 64);
        p2s += __shfl_xor(p2s, 2, 64);
        p2s += __shfl_xor(p2s, 4, 64);
        p2s += __shfl_xor(p2s, 8, 64);
        if (lr == 0) {
          atomicAdd(&g.s1a[row], p1s);
          atomicAdd(&g.s2a[row], p2s);
        }
      }
    }
  }

  if (EPI == 2) {
    // fused transpose: 128x64 tile of x2 -> LDS (stride 136) -> coalesced xT
    bf16* Ts = smem;
    __syncthreads();
#pragma unroll
    for (int i = 0; i < 4; i++)
#pragma unroll
      for (int v = 0; v < 4; v++)
#pragma unroll
        for (int j = 0; j < 2; j++) {
          int rloc = wm + i * 16 + lq * 4 + v;
          int cloc = (wn >> 1) + j * 16 + lr;
          Ts[cloc * 136 + rloc] = xn_arr[i][v][j];
        }
    __syncthreads();
    const int b = by >> 3;
    bf16* dst = g.xT + (long long)b * 524288 + ((by & 7) * 128);
#pragma unroll
    for (int it = 0; it < 2; it++) {
      int d = (tid >> 3) + it * 32;
      int jb = (tid & 7) * 16;
      bf16x8 v0 = *(const bf16x8*)(&Ts[d * 136 + jb]);
      bf16x8 v1 = *(const bf16x8*)(&Ts[d * 136 + jb + 8]);
      long long o = (long long)(bx * 64 + d) * 1024 + jb;
      *(bf16x8*)(dst + o) = v0;
      *(bf16x8*)(dst + o + 8) = v1;
    }
  }
}

// ============================ prep kernel ==================================
// Block-segmented:
//   [0,256)      : w1T = [tW|cW]^T via 64x64 LDS-tiled transpose (coalesced)
//   [256,512)    : w2T = [ffW|frW]^T likewise
//   [512,4608)   : fp32 inputs -> bf16 xb0 (coalesced; 4096 blocks)
//   [4608]       : biases + sred zeroing
__device__ __forceinline__ void tile_transpose(const float* src, int sld,
                                               bf16* dst, int dld,
                                               int k0, int n0, int tid) {
  __shared__ float tile[64][65];
  const int rr = tid >> 4, c4 = (tid & 15) * 4;
#pragma unroll
  for (int it = 0; it < 4; it++) {
    int r = rr + it * 16;
    f32x4 v = *(const f32x4*)(src + (long long)(k0 + r) * sld + n0 + c4);
    tile[r][c4] = v[0]; tile[r][c4 + 1] = v[1];
    tile[r][c4 + 2] = v[2]; tile[r][c4 + 3] = v[3];
  }
  __syncthreads();
  const int nl = tid >> 2, kb = (tid & 3) * 16;
  bf16x8 o0, o1;
#pragma unroll
  for (int kk = 0; kk < 8; kk++) o0[kk] = (bf16)tile[kb + kk][nl];
#pragma unroll
  for (int kk = 0; kk < 8; kk++) o1[kk] = (bf16)tile[kb + 8 + kk][nl];
  bf16* d = dst + (long long)(n0 + nl) * dld + k0 + kb;
  *(bf16x8*)d = o0;
  *(bf16x8*)(d + 8) = o1;
}

__global__ void prep(const float* tW, const float* tb, const float* cW, const float* cb,
                     const float* frW, const float* frb, const float* ffW, const float* ffb,
                     const float* inp, bf16* xb0,
                     bf16* w1T, bf16* w2T, float* bias1, float* bias2, float* sred) {
  const int bid = blockIdx.x, tid = threadIdx.x;
  if (bid < 256) {
    const int quad = bid >> 6, tile = bid & 63;
    const int l = quad >> 1, half = quad & 1;
    const float* src = (half ? cW : tW) + l * 262144;
    bf16* dst = w1T + l * 524288 + half * 262144;
    tile_transpose(src, 512, dst, 512, (tile >> 3) * 64, (tile & 7) * 64, tid);
  } else if (bid < 512) {
    const int j = bid - 256;
    const int half = j >> 7, tile = j & 127;
    const float* src = half ? frW : ffW;
    bf16* dst = w2T + half * 524288;
    tile_transpose(src, 512, dst, 1024, (tile >> 3) * 64, (tile & 7) * 64, tid);
  } else if (bid < 4608) {
    long long i8 = (((long long)(bid - 512)) * 256 + tid) * 8;
    bf16x8 o;
#pragma unroll
    for (int k = 0; k < 8; k++) o[k] = (bf16)inp[i8 + k];
    *(bf16x8*)(xb0 + i8) = o;
  } else {
    for (int j = tid; j < 3072; j += 256) {
      if (j < 2048) {
        int l = j >> 10, n = j & 1023;
        bias1[j] = (n < 512) ? tb[l * 512 + n] : cb[l * 512 + (n - 512)];
      } else {
        int n = j - 2048;
        bias2[n] = (n < 512) ? ffb[n] : frb[n - 512];
      }
    }
    for (int j = tid; j < 12288; j += 256)
      *(f32x4*)(sred + j * 4) = f32x4{0.f, 0.f, 0.f, 0.f};
  }
}

extern "C" void kernel_launch(void* const* d_in, const int* in_sizes, int n_in,
                              void* d_out, int out_size, void* d_ws, size_t ws_size,
                              hipStream_t stream) {
  const float* inp = (const float*)d_in[0];
  const float* tW  = (const float*)d_in[1];
  const float* tb  = (const float*)d_in[2];
  const float* cW  = (const float*)d_in[3];
  const float* cb  = (const float*)d_in[4];
  const float* aW  = (const float*)d_in[5];
  const float* ab  = (const float*)d_in[6];
  const float* frW = (const float*)d_in[7];
  const float* frb = (const float*)d_in[8];
  const float* ffW = (const float*)d_in[9];
  const float* ffb = (const float*)d_in[10];
  float* out = (float*)d_out;

  char* p = (char*)d_ws;
  auto alloc = [&](size_t bytes) { char* r = p; p += (bytes + 255) & ~size_t(255); return r; };
  bf16* xb0   = (bf16*) alloc(16777216);
  bf16* x1    = (bf16*) alloc(16777216);
  bf16* x2    = (bf16*) alloc(16777216);
  bf16* q16   = (bf16*) alloc(16777216);
  bf16* xT16  = (bf16*) alloc(16777216);
  bf16* att16 = (bf16*) alloc(16777216);
  bf16* E16   = (bf16*) alloc(33554432);
  float* sred = (float*)alloc(196608);     // s1 | s2 | lsum
  bf16* w1T   = (bf16*) alloc(2097152);
  bf16* w2T   = (bf16*) alloc(2097152);
  float* bias1= (float*)alloc(8192);
  float* bias2= (float*)alloc(4096);
  float* s1 = sred, *s2 = sred + 16384, *lsum = sred + 32768;

  prep<<<4609, 256, 0, stream>>>(
      tW, tb, cW, cb, frW, frb, ffW, ffb, inp, xb0, w1T, w2T, bias1, bias2, sred);

  {  // highway 1
    DualArgs g{};
    g.A = xb0; g.A2 = xb0; g.Bt = w1T;
    g.C = x1; g.xres = xb0;
    g.bias_t = bias1; g.bias_c = bias1 + 512;
    g.K = 512; g.ldb = 512;
    gemm_dual<0><<<1024, 256, 0, stream>>>(g);
  }
  {  // highway 2 + fused s1/s2/q + fused transpose
    DualArgs g{};
    g.A = x1; g.A2 = x1; g.Bt = w1T + 524288;
    g.C = x2; g.xres = x1;
    g.bias_t = bias1 + 1024; g.bias_c = bias1 + 1536;
    g.K = 512; g.ldb = 512;
    g.aW = aW; g.s1a = s1; g.s2a = s2; g.q = q16; g.xT = xT16;
    gemm_dual<2><<<1024, 256, 0, stream>>>(g);
  }
  {  // scores: E = exp(relu(Q K^T + s1 + s2 + ab)), row sums into lsum
    GemmArgs g{};
    g.A = q16; g.B = x2; g.C = E16;
    g.K = 512; g.lda = 512; g.ldb = 512; g.ldc = 1024;
    g.Ab = 524288; g.Bb = 524288; g.Cb = 1048576;
    g.s1 = s1; g.s2 = s2; g.abp = ab; g.lsum = lsum; g.L = 1024;
    g.gxsh = 3; g.gysh = 3;
    gemm_nt<1, 128><<<1024, 256, 0, stream>>>(g);
  }
  {  // att = (E @ x) / l -> att16   (128x64 tiles, 1024 blocks = 4/CU)
    GemmArgs g{};
    g.A = E16; g.B = xT16; g.C = att16;
    g.K = 1024; g.lda = 1024; g.ldb = 1024; g.ldc = 512;
    g.Ab = 1048576; g.Bb = 524288; g.Cb = 524288;
    g.s1 = lsum; g.L = 1024;
    g.gxsh = 3; g.gysh = 3;
    gemm_nt<4, 64><<<1024, 256, 0, stream>>>(g);
  }
  {  // final: out = r*x + z*z, z/r = sigmoid([xb0|att] @ [ffW|frW] + b)
    DualArgs g{};
    g.A = xb0; g.A2 = att16; g.Bt = w2T;
    g.C = out; g.xres = xb0;               // bf16 residual
    g.bias_t = bias2; g.bias_c = bias2 + 512;
    g.K = 1024; g.ldb = 1024;
    gemm_dual<1><<<1024, 256, 0, stream>>>(g);
  }
}